// Round 1
// baseline (690.415 us; speedup 1.0000x reference)
//
#include <hip/hip_runtime.h>
#include <hip/hip_fp16.h>

typedef _Float16 f16;
typedef _Float16 half8 __attribute__((ext_vector_type(8)));
typedef float f32x4 __attribute__((ext_vector_type(4)));

static __device__ __forceinline__ void fence_lds(){
  asm volatile("s_waitcnt lgkmcnt(0)" ::: "memory");
}

// ---------------- K0: W1 (128x128), W2 (128x288) -> transposed f16 ----------------
__global__ void k0_convert(const float* __restrict__ W1, const float* __restrict__ W2,
                           f16* __restrict__ W1T, f16* __restrict__ W2T){
  int o = blockIdx.x*256 + threadIdx.x;   // 208*256 = 53248 = 16384 + 36864 exactly
  if (o < 128*128){
    int j = o >> 7, i = o & 127;          // W1T[j][i] = W1[i][j]
    W1T[o] = (f16)W1[i*128 + j];
  } else {
    int o2 = o - 128*128;
    int n = o2 >> 7, i = o2 & 127;        // W2T[n][i] = W2[i][n]
    W2T[o2] = (f16)W2[i*288 + n];
  }
}

// ---------------- K1: per-edge overlaps -> h0[128] f16 (stored in outB row bytes) ----------------
__global__ __launch_bounds__(256) void k1_phase1(
    const float* __restrict__ x, const int* __restrict__ eidx,
    const float* __restrict__ efa, const float* __restrict__ efb,
    const float* __restrict__ em, f16* h0, int E)
{
  // per-wave scratch, f16, rows padded to 40 elements (80B, keeps 16B alignment, ~2-way banks)
  __shared__ f16 lds[4*3200];
  const int tid = threadIdx.x;
  const int l   = tid & 63;
  const int w   = tid >> 6;
  f16* Mb   = lds + w*3200;     // [32][40]
  f16* AXT  = Mb   + 32*40;     // [16][40]  rows: c(A) 0..7, c(Xa) 8..15 ; cols d
  f16* BXT  = AXT  + 16*40;     // [16][40]  rows: c(B) 0..7, c(Xb) 8..15
  f16* MBXT = BXT  + 16*40;     // [16][40]  rows: n of [MB|MXb], cols d
  const int q   = l >> 4;
  const int n16 = l & 15;

  const int wave_gid = blockIdx.x*4 + w;
  const int nwaves   = gridDim.x*4;
  for (int e = wave_gid; e < E; e += nwaves){
    const size_t eb = (size_t)e * 256;
    const int ia = eidx[e], ib = eidx[E + e];
    f32x4 fA  = *(const f32x4*)(efa + eb + l*4);
    f32x4 fB  = *(const f32x4*)(efb + eb + l*4);
    f32x4 fXa = *(const f32x4*)(x + (size_t)ia*256 + l*4);
    f32x4 fXb = *(const f32x4*)(x + (size_t)ib*256 + l*4);
    const size_t mb_ = (size_t)e * 1024;
    f32x4 fM0 = *(const f32x4*)(em + mb_ +   0 + l*4);
    f32x4 fM1 = *(const f32x4*)(em + mb_ + 256 + l*4);
    f32x4 fM2 = *(const f32x4*)(em + mb_ + 512 + l*4);
    f32x4 fM3 = *(const f32x4*)(em + mb_ + 768 + l*4);

    // stage transposed feature tiles: lane holds float4 at (d = l>>1, c = (l&1)*4 + j)
    {
      int d = l >> 1, cb = (l & 1)*4;
      #pragma unroll
      for (int j = 0; j < 4; ++j){
        int c = cb + j;
        AXT[c*40 + d]     = (f16)fA[j];
        AXT[(8+c)*40 + d] = (f16)fXa[j];
        BXT[c*40 + d]     = (f16)fB[j];
        BXT[(8+c)*40 + d] = (f16)fXb[j];
      }
    }
    // stage M rows: chunk qq covers row qq*8 + (l>>3), cols (l&7)*4..+3
    {
      int r0 = l >> 3, c0 = (l & 7)*4;
      f16* p0 = Mb + ( 0 + r0)*40 + c0;
      p0[0]=(f16)fM0[0]; p0[1]=(f16)fM0[1]; p0[2]=(f16)fM0[2]; p0[3]=(f16)fM0[3];
      f16* p1 = Mb + ( 8 + r0)*40 + c0;
      p1[0]=(f16)fM1[0]; p1[1]=(f16)fM1[1]; p1[2]=(f16)fM1[2]; p1[3]=(f16)fM1[3];
      f16* p2 = Mb + (16 + r0)*40 + c0;
      p2[0]=(f16)fM2[0]; p2[1]=(f16)fM2[1]; p2[2]=(f16)fM2[2]; p2[3]=(f16)fM2[3];
      f16* p3 = Mb + (24 + r0)*40 + c0;
      p3[0]=(f16)fM3[0]; p3[1]=(f16)fM3[1]; p3[2]=(f16)fM3[2]; p3[3]=(f16)fM3[3];
    }
    fence_lds();

    // mfma1: [MB|MXb](32x16) = M(32x32) @ [B|Xb](32x16), two 16-row tiles
    half8 bF  = *(half8*)(BXT + n16*40 + q*8);
    half8 aF0 = *(half8*)(Mb  + n16*40      + q*8);
    half8 aF1 = *(half8*)(Mb  + (16+n16)*40 + q*8);
    f32x4 z = {0.f,0.f,0.f,0.f};
    f32x4 d0 = __builtin_amdgcn_mfma_f32_16x16x32_f16(aF0, bF, z, 0,0,0);
    f32x4 d1 = __builtin_amdgcn_mfma_f32_16x16x32_f16(aF1, bF, z, 0,0,0);
    // write transposed: MBXT[n][row]; D row = rt*16 + 4q + j, col = n16
    {
      f16* p0 = MBXT + n16*40 + q*4;
      p0[0]=(f16)d0[0]; p0[1]=(f16)d0[1]; p0[2]=(f16)d0[2]; p0[3]=(f16)d0[3];
      f16* p1 = MBXT + n16*40 + 16 + q*4;
      p1[0]=(f16)d1[0]; p1[1]=(f16)d1[1]; p1[2]=(f16)d1[2]; p1[3]=(f16)d1[3];
    }
    fence_lds();

    // mfma2: [eo|no](16x16) = [A|Xa]^T(16x32) @ [MB|MXb](32x16)
    half8 aF2 = *(half8*)(AXT  + n16*40 + q*8);
    half8 bF2 = *(half8*)(MBXT + n16*40 + q*8);
    f32x4 d2 = __builtin_amdgcn_mfma_f32_16x16x32_f16(aF2, bF2, z, 0,0,0);

    // h0 row lives in this edge's own outB row bytes: f16 index e*512 + i (i<128)
    f16* hrow = h0 + (size_t)e*512;
    if (q < 2 && n16 < 8){
      #pragma unroll
      for (int j=0;j<4;++j) hrow[(4*q+j)*8 + n16] = (f16)d2[j];          // eo -> h[0:64]
    }
    if (q >= 2 && n16 >= 8){
      #pragma unroll
      for (int j=0;j<4;++j) hrow[64 + (4*(q-2)+j)*8 + (n16-8)] = (f16)d2[j]; // no -> h[64:128]
    }
  }
}

// ---------------- K2: batched MLP (16 edges) + normalize + output matmuls ----------------
__global__ __launch_bounds__(256) void k2_mlp(
    const float* __restrict__ x, const int* __restrict__ eidx,
    const float* __restrict__ efa, const float* __restrict__ efb,
    const f16* __restrict__ W1T, const f16* __restrict__ W2T,
    const float* __restrict__ b1, const float* __restrict__ lng,
    const float* __restrict__ lnb, const float* __restrict__ b2,
    const f16* h0, float* __restrict__ outA, float* outB, int E)
{
  __shared__ f16  sH0[16*128];      // swizzled: chunk ^= (row&7)
  __shared__ f16  sH1[16*128];
  __shared__ float sStat[4*16*2];
  __shared__ float sR[16*292];
  __shared__ f16  sP3[4*1920];      // per wave: LHS[32][40] + RHS_T[16][40]
  const int tid = threadIdx.x;
  const int l = tid & 63, w = tid >> 6, q = l >> 4, n16 = l & 15;
  const int e0 = blockIdx.x * 16;

  // load h0 tile (swizzled chunks of 8 f16)
  {
    int row = tid >> 4, ch = tid & 15;
    half8 v = *(const half8*)(h0 + (size_t)(e0 + row)*512 + ch*8);
    *(half8*)(sH0 + row*128 + ((ch ^ (row & 7))*8)) = v;
  }
  __syncthreads();

  // GEMM1: (16x128) @ W1(128x128); wave w -> col tiles 2w, 2w+1
  f32x4 acc[2] = {{0,0,0,0},{0,0,0,0}};
  #pragma unroll
  for (int ks = 0; ks < 4; ++ks){
    half8 aF = *(const half8*)(sH0 + n16*128 + (((ks*4 + q) ^ (n16 & 7))*8));
    #pragma unroll
    for (int c2 = 0; c2 < 2; ++c2){
      int ct = 2*w + c2;
      half8 bF = *(const half8*)(W1T + (size_t)(ct*16 + n16)*128 + ks*32 + q*8);
      acc[c2] = __builtin_amdgcn_mfma_f32_16x16x32_f16(aF, bF, acc[c2], 0,0,0);
    }
  }
  // epilogue: bias + silu
  float sv[2][4];
  #pragma unroll
  for (int c2=0;c2<2;++c2)
    #pragma unroll
    for (int j=0;j<4;++j){
      int col = (2*w + c2)*16 + n16;
      float v = acc[c2][j] + b1[col];
      sv[c2][j] = v / (1.f + __expf(-v));
    }
  // LN stats: reduce each row (edge) over this wave's 32 cols, then across waves via LDS
  #pragma unroll
  for (int j=0;j<4;++j){
    float s  = sv[0][j] + sv[1][j];
    float sq = sv[0][j]*sv[0][j] + sv[1][j]*sv[1][j];
    #pragma unroll
    for (int m=1;m<16;m<<=1){ s += __shfl_xor(s, m, 64); sq += __shfl_xor(sq, m, 64); }
    if (n16 == 0){ sStat[(w*16 + 4*q + j)*2] = s; sStat[(w*16 + 4*q + j)*2 + 1] = sq; }
  }
  __syncthreads();
  float mu[4], rs[4];
  #pragma unroll
  for (int j=0;j<4;++j){
    int row = 4*q + j;
    float s=0.f, sq=0.f;
    #pragma unroll
    for (int w2=0;w2<4;++w2){ s += sStat[(w2*16+row)*2]; sq += sStat[(w2*16+row)*2+1]; }
    float m_ = s * (1.f/128.f);
    mu[j] = m_;
    rs[j] = rsqrtf(sq * (1.f/128.f) - m_*m_ + 1e-5f);
  }
  #pragma unroll
  for (int c2=0;c2<2;++c2)
    #pragma unroll
    for (int j=0;j<4;++j){
      int col = (2*w + c2)*16 + n16;
      int row = 4*q + j;
      float hn = (sv[c2][j] - mu[j])*rs[j]*lng[col] + lnb[col];
      sH1[row*128 + (((col>>3) ^ (row&7))*8) + (col&7)] = (f16)hn;
    }
  __syncthreads();

  // GEMM2: (16x128) @ W2(128x288); wave w -> col tiles {w+4t}
  f32x4 acc2[5] = {{0,0,0,0},{0,0,0,0},{0,0,0,0},{0,0,0,0},{0,0,0,0}};
  #pragma unroll
  for (int ks=0;ks<4;++ks){
    half8 aF = *(const half8*)(sH1 + n16*128 + (((ks*4 + q) ^ (n16 & 7))*8));
    #pragma unroll
    for (int t=0;t<5;++t){
      int ct = w + 4*t;
      if (ct < 18){
        half8 bF = *(const half8*)(W2T + (size_t)(ct*16 + n16)*128 + ks*32 + q*8);
        acc2[t] = __builtin_amdgcn_mfma_f32_16x16x32_f16(aF, bF, acc2[t], 0,0,0);
      }
    }
  }
  #pragma unroll
  for (int t=0;t<5;++t){
    int ct = w + 4*t;
    if (ct < 18){
      #pragma unroll
      for (int j=0;j<4;++j){
        int col = ct*16 + n16, row = 4*q + j;
        sR[row*292 + col] = acc2[t][j] + b2[col];
      }
    }
  }
  __syncthreads();

  // phase 3: wave w handles 4 edges
  f16* LHS = sP3 + w*1920;   // [32][40]: cols 0..7 A, 8..15 Xa, 16..23 B, 24..31 Xb
  f16* RT  = LHS + 32*40;    // [16][40]: RHS^T, rows n (out col), cols k 0..31
  for (int le = w*4; le < w*4 + 4; ++le){
    const int e = e0 + le;
    // weights: lane l holds mlp_res[l*4 .. l*4+3] = matrix m=l>>4, flat (n16*4+j)
    f32x4 w4 = *(const f32x4*)(sR + le*292 + l*4);
    float ssq = w4[0]*w4[0] + w4[1]*w4[1] + w4[2]*w4[2] + w4[3]*w4[3];
    #pragma unroll
    for (int m=1;m<16;m<<=1) ssq += __shfl_xor(ssq, m, 64);
    float rn = 1.f / (sqrtf(ssq) + 1e-6f);
    // zero RT: 640 f16 = 320 dwords = 5*64
    {
      uint32_t* z32 = (uint32_t*)RT;
      z32[l] = 0u; z32[l+64] = 0u; z32[l+128] = 0u; z32[l+192] = 0u; z32[l+256] = 0u;
    }
    const int mm = l >> 4;
    const int kk = n16 >> 1;
    #pragma unroll
    for (int j=0;j<4;++j){
      int c = (l & 1)*4 + j;
      float f = sR[le*292 + 256 + mm*8 + c];
      f16 val = (f16)(w4[j] * rn * f * 0.5f);
      int nOut = c + (mm & 1)*8;
      int rk   = kk + ((mm & 1) << 4) + ((mm >> 1) << 3);
      RT[nOut*40 + rk] = val;
    }
    // LHS staging
    const size_t eb = (size_t)e*256;
    const int ia = eidx[e], ib = eidx[E + e];
    f32x4 gA  = *(const f32x4*)(efa + eb + l*4);
    f32x4 gB  = *(const f32x4*)(efb + eb + l*4);
    f32x4 gXa = *(const f32x4*)(x + (size_t)ia*256 + l*4);
    f32x4 gXb = *(const f32x4*)(x + (size_t)ib*256 + l*4);
    {
      int d = l >> 1, cb = (l & 1)*4;
      f16* pr = LHS + d*40 + cb;
      #pragma unroll
      for (int j=0;j<4;++j){
        pr[j]      = (f16)gA[j];
        pr[8+j]    = (f16)gXa[j];
        pr[16+j]   = (f16)gB[j];
        pr[24+j]   = (f16)gXb[j];
      }
    }
    fence_lds();
    // [out_a|out_b](32x16) = LHS(32x32) @ RHS(32x16)
    half8 bF = *(const half8*)(RT + n16*40 + q*8);
    f32x4 z = {0.f,0.f,0.f,0.f};
    float* obase = (n16 < 8) ? (outA + eb + n16) : (outB + eb + n16 - 8);
    #pragma unroll
    for (int rt=0;rt<2;++rt){
      half8 aF = *(const half8*)(LHS + (rt*16 + n16)*40 + q*8);
      f32x4 Dv = __builtin_amdgcn_mfma_f32_16x16x32_f16(aF, bF, z, 0,0,0);
      #pragma unroll
      for (int j=0;j<4;++j){
        int dR = rt*16 + 4*q + j;
        obase[dR*8] = Dv[j];
      }
    }
    fence_lds();
  }
}

extern "C" void kernel_launch(void* const* d_in, const int* in_sizes, int n_in,
                              void* d_out, int out_size, void* d_ws, size_t ws_size,
                              hipStream_t stream) {
  const float* x   = (const float*)d_in[0];
  const int*   ei  = (const int*)  d_in[1];
  const float* efa = (const float*)d_in[2];
  const float* efb = (const float*)d_in[3];
  const float* em  = (const float*)d_in[4];
  const float* W1  = (const float*)d_in[5];
  const float* b1  = (const float*)d_in[6];
  const float* lng = (const float*)d_in[7];
  const float* lnb = (const float*)d_in[8];
  const float* W2  = (const float*)d_in[9];
  const float* b2  = (const float*)d_in[10];
  const int E = in_sizes[1] / 2;

  float* outA = (float*)d_out;
  float* outB = outA + (size_t)E*256;
  f16* W1T = (f16*)d_ws;             // 128*128 f16
  f16* W2T = W1T + 128*128;          // 288*128 f16   (total ws use: 106,496 B)
  f16* h0  = (f16*)outB;             // h0 row e overlaid in outB row e's own bytes

  k0_convert<<<208, 256, 0, stream>>>(W1, W2, W1T, W2T);
  k1_phase1<<<8192, 256, 0, stream>>>(x, ei, efa, efb, em, h0, E);
  k2_mlp<<<E/16, 256, 0, stream>>>(x, ei, efa, efb, W1T, W2T, b1, lng, lnb, b2,
                                   h0, outA, outB, E);
}

// Round 3
// 488.087 us; speedup vs baseline: 1.4145x; 1.4145x over previous
//
#include <hip/hip_runtime.h>
#include <hip/hip_fp16.h>

typedef _Float16 f16;
typedef _Float16 half8 __attribute__((ext_vector_type(8)));
typedef float f32x4 __attribute__((ext_vector_type(4)));

static __device__ __forceinline__ void fence_lds(){
  asm volatile("s_waitcnt lgkmcnt(0)" ::: "memory");
  __builtin_amdgcn_sched_barrier(0);
}

// ---------------- K0: W1 (128x128), W2 (128x288) -> transposed f16 ----------------
__global__ void k0_convert(const float* __restrict__ W1, const float* __restrict__ W2,
                           f16* __restrict__ W1T, f16* __restrict__ W2T){
  int o = blockIdx.x*256 + threadIdx.x;   // 208*256 = 53248 = 16384 + 36864 exactly
  if (o < 128*128){
    int j = o >> 7, i = o & 127;          // W1T[j][i] = W1[i][j]
    W1T[o] = (f16)W1[i*128 + j];
  } else {
    int o2 = o - 128*128;
    int n = o2 >> 7, i = o2 & 127;        // W2T[n][i] = W2[i][n]
    W2T[o2] = (f16)W2[i*288 + n];
  }
}

struct ERegs { f32x4 a, b, xa, xb, m0, m1, m2, m3; };

static __device__ __forceinline__ ERegs load_edge(
    const float* __restrict__ x, const int* __restrict__ eidx,
    const float* __restrict__ efa, const float* __restrict__ efb,
    const float* __restrict__ em, int e, int E, int l){
  ERegs r;
  const size_t eb = (size_t)e * 256;
  const int ia = eidx[e], ib = eidx[E + e];
  r.a  = *(const f32x4*)(efa + eb + l*4);
  r.b  = *(const f32x4*)(efb + eb + l*4);
  r.xa = *(const f32x4*)(x + (size_t)ia*256 + l*4);
  r.xb = *(const f32x4*)(x + (size_t)ib*256 + l*4);
  const size_t mb = (size_t)e * 1024;
  r.m0 = *(const f32x4*)(em + mb +   0 + l*4);
  r.m1 = *(const f32x4*)(em + mb + 256 + l*4);
  r.m2 = *(const f32x4*)(em + mb + 512 + l*4);
  r.m3 = *(const f32x4*)(em + mb + 768 + l*4);
  return r;
}

// ---------------- fused: overlaps + MLP + normalize + output matmuls ----------------
// block = 256 thr (4 waves), 16 edges; wave w owns edges w*4..w*4+3 end-to-end.
// LDS total: 40960 + 25600 + 4096 + 4096 + 512 = 75264 B -> 2 blocks/CU.
__global__ __launch_bounds__(256) void k_fused(
    const float* __restrict__ x, const int* __restrict__ eidx,
    const float* __restrict__ efa, const float* __restrict__ efb,
    const float* __restrict__ em,
    const f16* __restrict__ W1T, const f16* __restrict__ W2T,
    const float* __restrict__ b1, const float* __restrict__ lng,
    const float* __restrict__ lnb, const float* __restrict__ b2,
    float* __restrict__ outA, float* outB, int E)
{
  __shared__ f16   sLHS[16*1280];   // per edge [32][40]: k-packed A|Xa|B|Xb direct layout
  __shared__ f16   sWk[12800];      // phase1: per-wave Mb/AXT/BXT/MBXT; after phase1: sR(f32)+RT
  __shared__ f16   sH0[16*128];     // h0 (swizzled chunks)
  __shared__ f16   sH1[16*128];     // h1 (swizzled chunks) -- separate buffer, R1-exact
  __shared__ float sStat[128];

  const int tid = threadIdx.x;
  const int l = tid & 63, w = tid >> 6, q = l >> 4, n16 = l & 15;
  const int e0 = blockIdx.x * 16;

  f16* Mb   = sWk + w*3200;     // [32][40]
  f16* AXT  = Mb + 1280;        // [16][40]  rows: c(A) 0..7, c(Xa) 8..15 ; cols d
  f16* BXT  = AXT + 640;        // [16][40]  rows: c(B) 0..7, c(Xb) 8..15
  f16* MBXT = BXT + 640;        // [16][40]  rows: n of [MB|MXb], cols i

  // ======== phase 1: overlaps -> sH0 (h0), stage sLHS ========
  ERegs cur = load_edge(x, eidx, efa, efb, em, e0 + w*4, E, l);
  #pragma unroll
  for (int i = 0; i < 4; ++i){
    const int le = w*4 + i;
    ERegs nxt;
    if (i < 3) nxt = load_edge(x, eidx, efa, efb, em, e0 + le + 1, E, l);

    // stage transposed tiles + direct-layout LHS (same register data)
    {
      int d = l >> 1, cb = (l & 1)*4;
      f16* Ld = sLHS + le*1280 + d*40;
      #pragma unroll
      for (int j = 0; j < 4; ++j){
        int c = cb + j;
        f16 va  = (f16)cur.a[j],  vxa = (f16)cur.xa[j];
        f16 vb  = (f16)cur.b[j],  vxb = (f16)cur.xb[j];
        AXT[c*40 + d]     = va;   AXT[(8+c)*40 + d] = vxa;
        BXT[c*40 + d]     = vb;   BXT[(8+c)*40 + d] = vxb;
        Ld[c] = va; Ld[8+c] = vxa; Ld[16+c] = vb; Ld[24+c] = vxb;
      }
      int r0 = l >> 3, c0 = (l & 7)*4;
      f16* p0 = Mb + ( 0 + r0)*40 + c0;
      p0[0]=(f16)cur.m0[0]; p0[1]=(f16)cur.m0[1]; p0[2]=(f16)cur.m0[2]; p0[3]=(f16)cur.m0[3];
      f16* p1 = Mb + ( 8 + r0)*40 + c0;
      p1[0]=(f16)cur.m1[0]; p1[1]=(f16)cur.m1[1]; p1[2]=(f16)cur.m1[2]; p1[3]=(f16)cur.m1[3];
      f16* p2 = Mb + (16 + r0)*40 + c0;
      p2[0]=(f16)cur.m2[0]; p2[1]=(f16)cur.m2[1]; p2[2]=(f16)cur.m2[2]; p2[3]=(f16)cur.m2[3];
      f16* p3 = Mb + (24 + r0)*40 + c0;
      p3[0]=(f16)cur.m3[0]; p3[1]=(f16)cur.m3[1]; p3[2]=(f16)cur.m3[2]; p3[3]=(f16)cur.m3[3];
    }
    fence_lds();

    // mfma1: [MB|MXb](32x16) = M(32x32) @ [B|Xb](32x16)
    half8 bF  = *(half8*)(BXT + n16*40 + q*8);
    half8 aF0 = *(half8*)(Mb  + n16*40      + q*8);
    half8 aF1 = *(half8*)(Mb  + (16+n16)*40 + q*8);
    f32x4 z = {0.f,0.f,0.f,0.f};
    f32x4 d0 = __builtin_amdgcn_mfma_f32_16x16x32_f16(aF0, bF, z, 0,0,0);
    f32x4 d1 = __builtin_amdgcn_mfma_f32_16x16x32_f16(aF1, bF, z, 0,0,0);
    {
      f16* p0 = MBXT + n16*40 + q*4;
      p0[0]=(f16)d0[0]; p0[1]=(f16)d0[1]; p0[2]=(f16)d0[2]; p0[3]=(f16)d0[3];
      f16* p1 = MBXT + n16*40 + 16 + q*4;
      p1[0]=(f16)d1[0]; p1[1]=(f16)d1[1]; p1[2]=(f16)d1[2]; p1[3]=(f16)d1[3];
    }
    fence_lds();

    // mfma2: [eo|no](16x16) = [A|Xa]^T(16x32) @ [MB|MXb](32x16)
    half8 aF2 = *(half8*)(AXT  + n16*40 + q*8);
    half8 bF2 = *(half8*)(MBXT + n16*40 + q*8);
    f32x4 d2 = __builtin_amdgcn_mfma_f32_16x16x32_f16(aF2, bF2, z, 0,0,0);

    // h0 row -> sH0[le], swizzled in chunks of 8: chunk ^= (row&7)
    if (q < 2 && n16 < 8){
      #pragma unroll
      for (int j=0;j<4;++j){
        int ch = 4*q + j;                              // i = ch*8 + n16  (eo -> h[0:64])
        sH0[le*128 + ((ch ^ (le & 7))*8) + n16] = (f16)d2[j];
      }
    }
    if (q >= 2 && n16 >= 8){
      #pragma unroll
      for (int j=0;j<4;++j){
        int ch = 8 + 4*(q-2) + j;                      // no -> h[64:128]
        sH0[le*128 + ((ch ^ (le & 7))*8) + (n16-8)] = (f16)d2[j];
      }
    }
    if (i < 3) cur = nxt;
    fence_lds();
  }
  __syncthreads();

  // ======== GEMM1: (16x128) @ W1(128x128); wave w -> col tiles 2w, 2w+1 ========
  f32x4 acc[2] = {{0,0,0,0},{0,0,0,0}};
  #pragma unroll
  for (int ks = 0; ks < 4; ++ks){
    half8 aF = *(const half8*)(sH0 + n16*128 + (((ks*4 + q) ^ (n16 & 7))*8));
    #pragma unroll
    for (int c2 = 0; c2 < 2; ++c2){
      int ct = 2*w + c2;
      half8 bF = *(const half8*)(W1T + (size_t)(ct*16 + n16)*128 + ks*32 + q*8);
      acc[c2] = __builtin_amdgcn_mfma_f32_16x16x32_f16(aF, bF, acc[c2], 0,0,0);
    }
  }
  // bias + silu
  float sv[2][4];
  #pragma unroll
  for (int c2=0;c2<2;++c2)
    #pragma unroll
    for (int j=0;j<4;++j){
      int col = (2*w + c2)*16 + n16;
      float v = acc[c2][j] + b1[col];
      sv[c2][j] = v / (1.f + __expf(-v));
    }
  // LN stats
  #pragma unroll
  for (int j=0;j<4;++j){
    float s  = sv[0][j] + sv[1][j];
    float sq = sv[0][j]*sv[0][j] + sv[1][j]*sv[1][j];
    #pragma unroll
    for (int m=1;m<16;m<<=1){ s += __shfl_xor(s, m, 64); sq += __shfl_xor(sq, m, 64); }
    if (n16 == 0){ sStat[(w*16 + 4*q + j)*2] = s; sStat[(w*16 + 4*q + j)*2 + 1] = sq; }
  }
  __syncthreads();
  float mu[4], rs[4];
  #pragma unroll
  for (int j=0;j<4;++j){
    int row = 4*q + j;
    float s=0.f, sq=0.f;
    #pragma unroll
    for (int w2=0;w2<4;++w2){ s += sStat[(w2*16+row)*2]; sq += sStat[(w2*16+row)*2+1]; }
    float m_ = s * (1.f/128.f);
    mu[j] = m_;
    rs[j] = rsqrtf(sq * (1.f/128.f) - m_*m_ + 1e-5f);
  }
  // h1 -> sH1 (separate buffer, R1-exact)
  #pragma unroll
  for (int c2=0;c2<2;++c2)
    #pragma unroll
    for (int j=0;j<4;++j){
      int col = (2*w + c2)*16 + n16;
      int row = 4*q + j;
      float hn = (sv[c2][j] - mu[j])*rs[j]*lng[col] + lnb[col];
      sH1[row*128 + (((col>>3) ^ (row&7))*8) + (col&7)] = (f16)hn;
    }
  __syncthreads();

  // ======== GEMM2: (16x128) @ W2(128x288) -> sR (f32, aliases dead phase-1 scratch) ========
  float* sR = (float*)sWk;         // [16][292] f32 = 18688 B (sWk is 25600 B)
  f32x4 acc2[5] = {{0,0,0,0},{0,0,0,0},{0,0,0,0},{0,0,0,0},{0,0,0,0}};
  #pragma unroll
  for (int ks=0;ks<4;++ks){
    half8 aF = *(const half8*)(sH1 + n16*128 + (((ks*4 + q) ^ (n16 & 7))*8));
    #pragma unroll
    for (int t=0;t<5;++t){
      int ct = w + 4*t;
      if (ct < 18){
        half8 bF = *(const half8*)(W2T + (size_t)(ct*16 + n16)*128 + ks*32 + q*8);
        acc2[t] = __builtin_amdgcn_mfma_f32_16x16x32_f16(aF, bF, acc2[t], 0,0,0);
      }
    }
  }
  #pragma unroll
  for (int t=0;t<5;++t){
    int ct = w + 4*t;
    if (ct < 18){
      #pragma unroll
      for (int j=0;j<4;++j){
        int col = ct*16 + n16, row = 4*q + j;
        sR[row*292 + col] = acc2[t][j] + b2[col];
      }
    }
  }
  __syncthreads();

  // ======== phase 3 (R1-exact epilogue): normalize weights, output matmuls ========
  f16* RT = sWk + 9344 + w*640;    // [16][40] RHS^T, after sR's 18688 B
  for (int i = 0; i < 4; ++i){
    const int le = w*4 + i;
    const int e  = e0 + le;
    // weights: lane l holds mlp_res[l*4 .. l*4+3] = matrix mm=l>>4, flat (n16*4+j)
    f32x4 w4 = *(const f32x4*)(sR + le*292 + l*4);
    float ssq = w4[0]*w4[0] + w4[1]*w4[1] + w4[2]*w4[2] + w4[3]*w4[3];
    #pragma unroll
    for (int m=1;m<16;m<<=1) ssq += __shfl_xor(ssq, m, 64);
    float rn = 1.f / (sqrtf(ssq) + 1e-6f);
    // zero RT: 640 f16 = 320 dwords = 5*64
    {
      uint32_t* z32 = (uint32_t*)RT;
      z32[l] = 0u; z32[l+64] = 0u; z32[l+128] = 0u; z32[l+192] = 0u; z32[l+256] = 0u;
    }
    const int mm = l >> 4;
    const int kk = n16 >> 1;
    #pragma unroll
    for (int j=0;j<4;++j){
      int c = (l & 1)*4 + j;
      float f = sR[le*292 + 256 + mm*8 + c];
      f16 val = (f16)(w4[j] * rn * f * 0.5f);
      int nOut = c + (mm & 1)*8;
      int rk   = kk + ((mm & 1) << 4) + ((mm >> 1) << 3);
      RT[nOut*40 + rk] = val;
    }
    fence_lds();
    // [out_a|out_b](32x16) = LHS(32x32) @ RHS(32x16); direct strided stores (R1-exact)
    half8 bF = *(const half8*)(RT + n16*40 + q*8);
    const f16* Le = sLHS + le*1280;
    f32x4 z = {0.f,0.f,0.f,0.f};
    const size_t eb = (size_t)e * 256;
    float* obase = (n16 < 8) ? (outA + eb + n16) : (outB + eb + n16 - 8);
    #pragma unroll
    for (int rt=0;rt<2;++rt){
      half8 aF = *(const half8*)(Le + (rt*16 + n16)*40 + q*8);
      f32x4 Dv = __builtin_amdgcn_mfma_f32_16x16x32_f16(aF, bF, z, 0,0,0);
      #pragma unroll
      for (int j=0;j<4;++j){
        int dR = rt*16 + 4*q + j;
        obase[dR*8] = Dv[j];
      }
    }
    fence_lds();
  }
}

extern "C" void kernel_launch(void* const* d_in, const int* in_sizes, int n_in,
                              void* d_out, int out_size, void* d_ws, size_t ws_size,
                              hipStream_t stream) {
  const float* x   = (const float*)d_in[0];
  const int*   ei  = (const int*)  d_in[1];
  const float* efa = (const float*)d_in[2];
  const float* efb = (const float*)d_in[3];
  const float* em  = (const float*)d_in[4];
  const float* W1  = (const float*)d_in[5];
  const float* b1  = (const float*)d_in[6];
  const float* lng = (const float*)d_in[7];
  const float* lnb = (const float*)d_in[8];
  const float* W2  = (const float*)d_in[9];
  const float* b2  = (const float*)d_in[10];
  const int E = in_sizes[1] / 2;

  float* outA = (float*)d_out;
  float* outB = outA + (size_t)E*256;
  f16* W1T = (f16*)d_ws;             // 128*128 f16
  f16* W2T = W1T + 128*128;          // 288*128 f16

  k0_convert<<<208, 256, 0, stream>>>(W1, W2, W1T, W2T);
  k_fused<<<E/16, 256, 0, stream>>>(x, ei, efa, efb, em, W1T, W2T,
                                    b1, lng, lnb, b2, outA, outB, E);
}

// Round 5
// 476.723 us; speedup vs baseline: 1.4483x; 1.0238x over previous
//
#include <hip/hip_runtime.h>
#include <hip/hip_fp16.h>

typedef _Float16 f16;
typedef _Float16 half8 __attribute__((ext_vector_type(8)));
typedef _Float16 half4 __attribute__((ext_vector_type(4)));
typedef float f32x4 __attribute__((ext_vector_type(4)));

static __device__ __forceinline__ void fence_lds(){
  asm volatile("s_waitcnt lgkmcnt(0)" ::: "memory");
  __builtin_amdgcn_sched_barrier(0);
}

// ---------------- K0: W1 (128x128), W2 (128x288) -> transposed f16 ----------------
__global__ void k0_convert(const float* __restrict__ W1, const float* __restrict__ W2,
                           f16* __restrict__ W1T, f16* __restrict__ W2T){
  int o = blockIdx.x*256 + threadIdx.x;   // 208*256 = 53248 = 16384 + 36864 exactly
  if (o < 128*128){
    int j = o >> 7, i = o & 127;          // W1T[j][i] = W1[i][j]
    W1T[o] = (f16)W1[i*128 + j];
  } else {
    int o2 = o - 128*128;
    int n = o2 >> 7, i = o2 & 127;        // W2T[n][i] = W2[i][n]
    W2T[o2] = (f16)W2[i*288 + n];
  }
}

struct ERegs { f32x4 a, b, xa, xb, m0, m1, m2, m3; };

static __device__ __forceinline__ ERegs load_edge(
    const float* __restrict__ x, const int* __restrict__ eidx,
    const float* __restrict__ efa, const float* __restrict__ efb,
    const float* __restrict__ em, int e, int E, int l){
  ERegs r;
  const size_t eb = (size_t)e * 256;
  const int ia = eidx[e], ib = eidx[E + e];
  r.a  = *(const f32x4*)(efa + eb + l*4);
  r.b  = *(const f32x4*)(efb + eb + l*4);
  r.xa = *(const f32x4*)(x + (size_t)ia*256 + l*4);
  r.xb = *(const f32x4*)(x + (size_t)ib*256 + l*4);
  const size_t mb = (size_t)e * 1024;
  r.m0 = *(const f32x4*)(em + mb +   0 + l*4);
  r.m1 = *(const f32x4*)(em + mb + 256 + l*4);
  r.m2 = *(const f32x4*)(em + mb + 512 + l*4);
  r.m3 = *(const f32x4*)(em + mb + 768 + l*4);
  return r;
}

// ---------------- fused: overlaps + MLP + normalize + output matmuls ----------------
// block = 256 thr (4 waves), 16 edges; wave w owns edges w*4..w*4+3 end-to-end.
// LDS: sWk 34048 + sH0 4096 + sH1 4096 + sStat 512 = 42752 B -> 3 blocks/CU (12 waves/CU).
// sWk phase-1: per-wave Mb/AXT/BXT/MBXT (12800 f16).
// sWk phase-3: sR f32[16][292] (= 9344 f16) + per-wave {LHSst[32][40], RT[16][40]} (1920 f16 ea) = 17024 f16 exact.
__global__ __launch_bounds__(256, 3) void k_fused(
    const float* __restrict__ x, const int* __restrict__ eidx,
    const float* __restrict__ efa, const float* __restrict__ efb,
    const float* __restrict__ em,
    const f16* __restrict__ W1T, const f16* __restrict__ W2T,
    const float* __restrict__ b1, const float* __restrict__ lng,
    const float* __restrict__ lnb, const float* __restrict__ b2,
    float* __restrict__ outA, float* outB, int E)
{
  __shared__ f16   sWk[17024];
  __shared__ f16   sH0[16*128];     // h0 (swizzled chunks)
  __shared__ f16   sH1[16*128];     // h1 (swizzled chunks)
  __shared__ float sStat[128];

  const int tid = threadIdx.x;
  const int l = tid & 63, w = tid >> 6, q = l >> 4, n16 = l & 15;
  const int e0 = blockIdx.x * 16;

  f16* Mb   = sWk + w*3200;     // [32][40]
  f16* AXT  = Mb + 1280;        // [16][40]  rows: c(A) 0..7, c(Xa) 8..15 ; cols d
  f16* BXT  = AXT + 640;        // [16][40]  rows: c(B) 0..7, c(Xb) 8..15
  f16* MBXT = BXT + 640;        // [16][40]  rows: n of [MB|MXb], cols i

  // per-edge feature fragments held in registers (statically indexed; loops unrolled)
  half4 hA[4], hXa[4], hB[4], hXb[4];

  // ======== phase 1: overlaps -> sH0 (h0) ========
  ERegs cur = load_edge(x, eidx, efa, efb, em, e0 + w*4, E, l);
  #pragma unroll
  for (int i = 0; i < 4; ++i){
    const int le = w*4 + i;
    ERegs nxt;
    if (i < 3) nxt = load_edge(x, eidx, efa, efb, em, e0 + le + 1, E, l);

    // stage transposed tiles; keep direct-layout fragments in registers
    {
      int d = l >> 1, cb = (l & 1)*4;
      half4 ta, txa, tb, txb;
      #pragma unroll
      for (int j = 0; j < 4; ++j){
        int c = cb + j;
        f16 va  = (f16)cur.a[j],  vxa = (f16)cur.xa[j];
        f16 vb  = (f16)cur.b[j],  vxb = (f16)cur.xb[j];
        AXT[c*40 + d]     = va;   AXT[(8+c)*40 + d] = vxa;
        BXT[c*40 + d]     = vb;   BXT[(8+c)*40 + d] = vxb;
        ta[j] = va; txa[j] = vxa; tb[j] = vb; txb[j] = vxb;
      }
      hA[i] = ta; hXa[i] = txa; hB[i] = tb; hXb[i] = txb;
      int r0 = l >> 3, c0 = (l & 7)*4;
      f16* p0 = Mb + ( 0 + r0)*40 + c0;
      p0[0]=(f16)cur.m0[0]; p0[1]=(f16)cur.m0[1]; p0[2]=(f16)cur.m0[2]; p0[3]=(f16)cur.m0[3];
      f16* p1 = Mb + ( 8 + r0)*40 + c0;
      p1[0]=(f16)cur.m1[0]; p1[1]=(f16)cur.m1[1]; p1[2]=(f16)cur.m1[2]; p1[3]=(f16)cur.m1[3];
      f16* p2 = Mb + (16 + r0)*40 + c0;
      p2[0]=(f16)cur.m2[0]; p2[1]=(f16)cur.m2[1]; p2[2]=(f16)cur.m2[2]; p2[3]=(f16)cur.m2[3];
      f16* p3 = Mb + (24 + r0)*40 + c0;
      p3[0]=(f16)cur.m3[0]; p3[1]=(f16)cur.m3[1]; p3[2]=(f16)cur.m3[2]; p3[3]=(f16)cur.m3[3];
    }
    fence_lds();

    // mfma1: [MB|MXb](32x16) = M(32x32) @ [B|Xb](32x16)
    half8 bF  = *(half8*)(BXT + n16*40 + q*8);
    half8 aF0 = *(half8*)(Mb  + n16*40      + q*8);
    half8 aF1 = *(half8*)(Mb  + (16+n16)*40 + q*8);
    f32x4 z = {0.f,0.f,0.f,0.f};
    f32x4 d0 = __builtin_amdgcn_mfma_f32_16x16x32_f16(aF0, bF, z, 0,0,0);
    f32x4 d1 = __builtin_amdgcn_mfma_f32_16x16x32_f16(aF1, bF, z, 0,0,0);
    {
      f16* p0 = MBXT + n16*40 + q*4;
      p0[0]=(f16)d0[0]; p0[1]=(f16)d0[1]; p0[2]=(f16)d0[2]; p0[3]=(f16)d0[3];
      f16* p1 = MBXT + n16*40 + 16 + q*4;
      p1[0]=(f16)d1[0]; p1[1]=(f16)d1[1]; p1[2]=(f16)d1[2]; p1[3]=(f16)d1[3];
    }
    fence_lds();

    // mfma2: [eo|no](16x16) = [A|Xa]^T(16x32) @ [MB|MXb](32x16)
    half8 aF2 = *(half8*)(AXT  + n16*40 + q*8);
    half8 bF2 = *(half8*)(MBXT + n16*40 + q*8);
    f32x4 d2 = __builtin_amdgcn_mfma_f32_16x16x32_f16(aF2, bF2, z, 0,0,0);

    // h0 row -> sH0[le], swizzled in chunks of 8: chunk ^= (row&7)
    if (q < 2 && n16 < 8){
      #pragma unroll
      for (int j=0;j<4;++j){
        int ch = 4*q + j;                              // i = ch*8 + n16  (eo -> h[0:64])
        sH0[le*128 + ((ch ^ (le & 7))*8) + n16] = (f16)d2[j];
      }
    }
    if (q >= 2 && n16 >= 8){
      #pragma unroll
      for (int j=0;j<4;++j){
        int ch = 8 + 4*(q-2) + j;                      // no -> h[64:128]
        sH0[le*128 + ((ch ^ (le & 7))*8) + (n16-8)] = (f16)d2[j];
      }
    }
    if (i < 3) cur = nxt;
    fence_lds();
  }
  __syncthreads();

  // ======== GEMM1: (16x128) @ W1(128x128); wave w -> col tiles 2w, 2w+1 ========
  f32x4 acc[2] = {{0,0,0,0},{0,0,0,0}};
  #pragma unroll
  for (int ks = 0; ks < 4; ++ks){
    half8 aF = *(const half8*)(sH0 + n16*128 + (((ks*4 + q) ^ (n16 & 7))*8));
    #pragma unroll
    for (int c2 = 0; c2 < 2; ++c2){
      int ct = 2*w + c2;
      half8 bF = *(const half8*)(W1T + (size_t)(ct*16 + n16)*128 + ks*32 + q*8);
      acc[c2] = __builtin_amdgcn_mfma_f32_16x16x32_f16(aF, bF, acc[c2], 0,0,0);
    }
  }
  // bias + silu
  float sv[2][4];
  #pragma unroll
  for (int c2=0;c2<2;++c2)
    #pragma unroll
    for (int j=0;j<4;++j){
      int col = (2*w + c2)*16 + n16;
      float v = acc[c2][j] + b1[col];
      sv[c2][j] = v / (1.f + __expf(-v));
    }
  // LN stats
  #pragma unroll
  for (int j=0;j<4;++j){
    float s  = sv[0][j] + sv[1][j];
    float sq = sv[0][j]*sv[0][j] + sv[1][j]*sv[1][j];
    #pragma unroll
    for (int m=1;m<16;m<<=1){ s += __shfl_xor(s, m, 64); sq += __shfl_xor(sq, m, 64); }
    if (n16 == 0){ sStat[(w*16 + 4*q + j)*2] = s; sStat[(w*16 + 4*q + j)*2 + 1] = sq; }
  }
  __syncthreads();
  float mu[4], rs[4];
  #pragma unroll
  for (int j=0;j<4;++j){
    int row = 4*q + j;
    float s=0.f, sq=0.f;
    #pragma unroll
    for (int w2=0;w2<4;++w2){ s += sStat[(w2*16+row)*2]; sq += sStat[(w2*16+row)*2+1]; }
    float m_ = s * (1.f/128.f);
    mu[j] = m_;
    rs[j] = rsqrtf(sq * (1.f/128.f) - m_*m_ + 1e-5f);
  }
  // h1 -> sH1
  #pragma unroll
  for (int c2=0;c2<2;++c2)
    #pragma unroll
    for (int j=0;j<4;++j){
      int col = (2*w + c2)*16 + n16;
      int row = 4*q + j;
      float hn = (sv[c2][j] - mu[j])*rs[j]*lng[col] + lnb[col];
      sH1[row*128 + (((col>>3) ^ (row&7))*8) + (col&7)] = (f16)hn;
    }
  __syncthreads();

  // ======== GEMM2: (16x128) @ W2(128x288) -> sR (f32, aliases dead phase-1 scratch) ========
  float* sR = (float*)sWk;         // [16][292] f32 = 18688 B
  f32x4 acc2[5] = {{0,0,0,0},{0,0,0,0},{0,0,0,0},{0,0,0,0},{0,0,0,0}};
  #pragma unroll
  for (int ks=0;ks<4;++ks){
    half8 aF = *(const half8*)(sH1 + n16*128 + (((ks*4 + q) ^ (n16 & 7))*8));
    #pragma unroll
    for (int t=0;t<5;++t){
      int ct = w + 4*t;
      if (ct < 18){
        half8 bF = *(const half8*)(W2T + (size_t)(ct*16 + n16)*128 + ks*32 + q*8);
        acc2[t] = __builtin_amdgcn_mfma_f32_16x16x32_f16(aF, bF, acc2[t], 0,0,0);
      }
    }
  }
  #pragma unroll
  for (int t=0;t<5;++t){
    int ct = w + 4*t;
    if (ct < 18){
      #pragma unroll
      for (int j=0;j<4;++j){
        int col = ct*16 + n16, row = 4*q + j;
        sR[row*292 + col] = acc2[t][j] + b2[col];
      }
    }
  }
  __syncthreads();

  // ======== phase 3 (R3-exact except LHS source): normalize weights, output matmuls ========
  f16* pw    = sWk + 9344 + w*1920;   // after sR's 18688 B (= 9344 f16)
  f16* LHSst = pw;                    // [32][40]
  f16* RT    = pw + 1280;             // [16][40] RHS^T
  #pragma unroll
  for (int i = 0; i < 4; ++i){
    const int le = w*4 + i;
    const int e  = e0 + le;
    // weights: lane l holds mlp_res[l*4 .. l*4+3] = matrix mm=l>>4, flat (n16*4+j)
    f32x4 w4 = *(const f32x4*)(sR + le*292 + l*4);
    float ssq = w4[0]*w4[0] + w4[1]*w4[1] + w4[2]*w4[2] + w4[3]*w4[3];
    #pragma unroll
    for (int m=1;m<16;m<<=1) ssq += __shfl_xor(ssq, m, 64);
    float rn = 1.f / (sqrtf(ssq) + 1e-6f);
    // zero RT: 640 f16 = 320 dwords = 5*64
    {
      uint32_t* z32 = (uint32_t*)RT;
      z32[l] = 0u; z32[l+64] = 0u; z32[l+128] = 0u; z32[l+192] = 0u; z32[l+256] = 0u;
    }
    const int mm = l >> 4;
    const int kk = n16 >> 1;
    #pragma unroll
    for (int j=0;j<4;++j){
      int c = (l & 1)*4 + j;
      float f = sR[le*292 + 256 + mm*8 + c];
      f16 val = (f16)(w4[j] * rn * f * 0.5f);
      int nOut = c + (mm & 1)*8;
      int rk   = kk + ((mm & 1) << 4) + ((mm >> 1) << 3);
      RT[nOut*40 + rk] = val;
    }
    // stage LHS from held registers: row d, cols 0..7 A, 8..15 Xa, 16..23 B, 24..31 Xb
    {
      int d = l >> 1, cb = (l & 1)*4;
      *(half4*)(LHSst + d*40 + cb)      = hA[i];
      *(half4*)(LHSst + d*40 + 8 + cb)  = hXa[i];
      *(half4*)(LHSst + d*40 + 16 + cb) = hB[i];
      *(half4*)(LHSst + d*40 + 24 + cb) = hXb[i];
    }
    fence_lds();
    // [out_a|out_b](32x16) = LHS(32x32) @ RHS(32x16); direct strided stores
    half8 bF = *(const half8*)(RT + n16*40 + q*8);
    f32x4 z = {0.f,0.f,0.f,0.f};
    const size_t eb = (size_t)e * 256;
    float* obase = (n16 < 8) ? (outA + eb + n16) : (outB + eb + n16 - 8);
    #pragma unroll
    for (int rt=0;rt<2;++rt){
      half8 aF = *(const half8*)(LHSst + (rt*16 + n16)*40 + q*8);
      f32x4 Dv = __builtin_amdgcn_mfma_f32_16x16x32_f16(aF, bF, z, 0,0,0);
      #pragma unroll
      for (int j=0;j<4;++j){
        int dR = rt*16 + 4*q + j;
        obase[dR*8] = Dv[j];
      }
    }
    fence_lds();
  }
}

extern "C" void kernel_launch(void* const* d_in, const int* in_sizes, int n_in,
                              void* d_out, int out_size, void* d_ws, size_t ws_size,
                              hipStream_t stream) {
  const float* x   = (const float*)d_in[0];
  const int*   ei  = (const int*)  d_in[1];
  const float* efa = (const float*)d_in[2];
  const float* efb = (const float*)d_in[3];
  const float* em  = (const float*)d_in[4];
  const float* W1  = (const float*)d_in[5];
  const float* b1  = (const float*)d_in[6];
  const float* lng = (const float*)d_in[7];
  const float* lnb = (const float*)d_in[8];
  const float* W2  = (const float*)d_in[9];
  const float* b2  = (const float*)d_in[10];
  const int E = in_sizes[1] / 2;

  float* outA = (float*)d_out;
  float* outB = outA + (size_t)E*256;
  f16* W1T = (f16*)d_ws;             // 128*128 f16
  f16* W2T = W1T + 128*128;          // 288*128 f16

  k0_convert<<<208, 256, 0, stream>>>(W1, W2, W1T, W2T);
  k_fused<<<E/16, 256, 0, stream>>>(x, ei, efa, efb, em, W1T, W2T,
                                    b1, lng, lnb, b2, outA, outB, E);
}